// Round 1
// baseline (86.821 us; speedup 1.0000x reference)
//
#include <hip/hip_runtime.h>
#include <hip/hip_bf16.h>

#define BSZ 4096
#define NSZ 8192
#define DD  128
#define TILE 128
#define INV_TAU 10.0f

typedef __attribute__((ext_vector_type(8))) short bf16x8;
typedef __attribute__((ext_vector_type(4))) float f32x4;

// ---------------- Kernel 1: normalize rows of reps=[zjs; zis] -> bf16 ----------------
__global__ void norm_kernel(const float* __restrict__ zis,
                            const float* __restrict__ zjs,
                            __hip_bfloat16* __restrict__ rn) {
    int row = blockIdx.x;          // 0..8191
    int t = threadIdx.x;           // 0..127
    const float* src = (row < BSZ) ? (zjs + (size_t)row * DD)
                                   : (zis + (size_t)(row - BSZ) * DD);
    float x = src[t];
    float ss = x * x;
    #pragma unroll
    for (int off = 32; off; off >>= 1) ss += __shfl_xor(ss, off);
    __shared__ float red[2];
    if ((t & 63) == 0) red[t >> 6] = ss;
    __syncthreads();
    float tot = red[0] + red[1];
    float inv = 1.0f / fmaxf(sqrtf(tot), 1e-8f);
    rn[(size_t)row * DD + t] = __float2bfloat16(x * inv);
}

// ---------------- Kernel 2: fused sim GEMM + exp + per-row sum ----------------
// grid (64, 64): bj = blockIdx.x (col tile), bi = blockIdx.y (row tile)
// 256 threads = 4 waves; wave w computes rows [w*32, w*32+32) x 128 cols.
__global__ __launch_bounds__(256, 2)
void sim_lse_kernel(const __hip_bfloat16* __restrict__ rn,
                    float* __restrict__ sumexp,
                    float* __restrict__ pos) {
    __shared__ ushort At[TILE * DD];   // 32 KB, XOR-swizzled
    __shared__ ushort Bt[TILE * DD];   // 32 KB, XOR-swizzled

    const int bj = blockIdx.x;
    const int bi = blockIdx.y;
    const int tid = threadIdx.x;

    // ---- stage both tiles (each is a contiguous 32KB chunk of rn) ----
    const uint4* asrc = (const uint4*)(rn + (size_t)bi * TILE * DD);
    const uint4* bsrc = (const uint4*)(rn + (size_t)bj * TILE * DD);
    uint4* adst = (uint4*)At;
    uint4* bdst = (uint4*)Bt;
    #pragma unroll
    for (int it = 0; it < 8; ++it) {
        int c = it * 256 + tid;        // uint4 chunk index, 16 chunks per row
        int row = c >> 4;
        int sw = c ^ (row & 7);        // byte ^= (row&7)<<4, chunk granularity
        adst[sw] = asrc[c];
        bdst[sw] = bsrc[c];
    }
    __syncthreads();

    const int wid  = tid >> 6;
    const int lane = tid & 63;
    const int l15  = lane & 15;
    const int kg   = lane >> 4;        // 0..3
    const int lr0  = wid * 32;         // wave's local row base

    f32x4 acc[2][8] = {};
    const char* Ab = (const char*)At;
    const char* Bb = (const char*)Bt;

    #pragma unroll
    for (int kk = 0; kk < 4; ++kk) {
        int kb = kk * 64 + kg * 16;    // byte offset of this lane's k-slice
        bf16x8 af[2], bfr[8];
        #pragma unroll
        for (int mt = 0; mt < 2; ++mt) {
            int r = lr0 + mt * 16 + l15;
            int o = r * 256 + kb;
            af[mt] = *(const bf16x8*)(Ab + (o ^ ((r & 7) << 4)));
        }
        #pragma unroll
        for (int cf = 0; cf < 8; ++cf) {
            int cR = cf * 16 + l15;
            int o = cR * 256 + kb;
            bfr[cf] = *(const bf16x8*)(Bb + (o ^ ((cR & 7) << 4)));
        }
        #pragma unroll
        for (int mt = 0; mt < 2; ++mt)
            #pragma unroll
            for (int cf = 0; cf < 8; ++cf)
                acc[mt][cf] = __builtin_amdgcn_mfma_f32_16x16x32_bf16(
                    af[mt], bfr[cf], acc[mt][cf], 0, 0, 0);
    }

    // ---- epilogue: exp + per-row partial sums + pos capture ----
    const int rowbase = bi * TILE + lr0;
    const int colbase = bj * TILE;
    const bool diagblk = (bi == bj);
    const bool posblk  = (bj == ((bi + 32) & 63));

    #pragma unroll
    for (int mt = 0; mt < 2; ++mt) {
        float psum[4] = {0.f, 0.f, 0.f, 0.f};
        #pragma unroll
        for (int cf = 0; cf < 8; ++cf) {
            #pragma unroll
            for (int reg = 0; reg < 4; ++reg) {
                float s = acc[mt][cf][reg];
                int r = rowbase + mt * 16 + kg * 4 + reg;
                int c = colbase + cf * 16 + l15;
                if (posblk && ((c - r) == BSZ || (r - c) == BSZ)) pos[r] = s;
                float p = (diagblk && r == c) ? 0.0f : __expf(s * INV_TAU);
                psum[reg] += p;
            }
        }
        #pragma unroll
        for (int reg = 0; reg < 4; ++reg) {
            float v = psum[reg];
            v += __shfl_xor(v, 1);
            v += __shfl_xor(v, 2);
            v += __shfl_xor(v, 4);
            v += __shfl_xor(v, 8);
            if (l15 == 0)
                atomicAdd(&sumexp[rowbase + mt * 16 + kg * 4 + reg], v);
        }
    }
}

// ---------------- Kernel 3: final scalar reduction ----------------
__global__ void reduce_kernel(const float* __restrict__ sumexp,
                              const float* __restrict__ pos,
                              float* __restrict__ out) {
    int tid = threadIdx.x;  // 256
    float ce = 0.f, pt = 0.f;
    for (int i = tid; i < NSZ; i += 256) {
        float se = sumexp[i];
        float p  = pos[i];
        ce += __logf(se) - p * INV_TAU;
        pt += __expf(p * INV_TAU) / se;
    }
    #pragma unroll
    for (int off = 32; off; off >>= 1) {
        ce += __shfl_xor(ce, off);
        pt += __shfl_xor(pt, off);
    }
    __shared__ float lce[4], lpt[4];
    if ((tid & 63) == 0) { lce[tid >> 6] = ce; lpt[tid >> 6] = pt; }
    __syncthreads();
    if (tid == 0) {
        float CE = lce[0] + lce[1] + lce[2] + lce[3];
        float PT = lpt[0] + lpt[1] + lpt[2] + lpt[3];
        float loss = CE / (float)NSZ + 1.0f
                   - PT * ((float)BSZ / ((float)NSZ * (float)(NSZ - 1)));
        out[0] = loss;
    }
}

extern "C" void kernel_launch(void* const* d_in, const int* in_sizes, int n_in,
                              void* d_out, int out_size, void* d_ws, size_t ws_size,
                              hipStream_t stream) {
    const float* zis = (const float*)d_in[0];
    const float* zjs = (const float*)d_in[1];
    float* out = (float*)d_out;

    char* ws = (char*)d_ws;
    __hip_bfloat16* rn = (__hip_bfloat16*)ws;                 // 2 MB
    float* sumexp = (float*)(ws + 2 * 1024 * 1024);           // 32 KB
    float* pos    = (float*)(ws + 2 * 1024 * 1024 + 32768);   // 32 KB

    hipMemsetAsync(sumexp, 0, NSZ * sizeof(float), stream);

    norm_kernel<<<NSZ, 128, 0, stream>>>(zis, zjs, rn);

    dim3 grid(64, 64);
    sim_lse_kernel<<<grid, 256, 0, stream>>>(rn, sumexp, pos);

    reduce_kernel<<<1, 256, 0, stream>>>(sumexp, pos, out);
}